// Round 4
// baseline (62.012 us; speedup 1.0000x reference)
//
#include <hip/hip_runtime.h>
#include <hip/hip_bf16.h>

// LengthRegulator: x (B,S,D) f32, durations (B,S) int.
// dur = clip(dur,1,None); cum = cumsum(dur, axis=1); totals = cum[:,-1];
// out[b,p,:] = x[b, searchsorted_right(cum[b], p) clipped S-1, :] for p < totals[b], else 0.
// Output (B, max_len, D), max_len = out_size/(B*D).

constexpr int B = 32;
constexpr int S = 1024;
constexpr int D = 512;
constexpr int VEC_PER_ROW = D / 4;       // 128 float4 per row

using f4 = __attribute__((ext_vector_type(4))) float;

// ---- Kernel A: per-batch scan (wave-scan, 4 elems/thread) + scatter --------
// idx_map[b*max_len + p] = absolute source row (b*S+s), or -1 in masked tail.
__global__ void lr_scan_scatter(const int* __restrict__ durations,
                                int* __restrict__ idx_map,
                                int max_len) {
    const int b    = blockIdx.x;
    const int t    = threadIdx.x;        // 0..255
    const int lane = t & 63;
    const int wv   = t >> 6;             // wave id 0..3

    int4 d4 = reinterpret_cast<const int4*>(durations + b * S)[t];
    const int d0 = d4.x < 1 ? 1 : d4.x;
    const int d1 = d4.y < 1 ? 1 : d4.y;
    const int d2 = d4.z < 1 ? 1 : d4.z;
    const int d3 = d4.w < 1 ? 1 : d4.w;
    const int tsum = d0 + d1 + d2 + d3;

    // inclusive wave scan of per-thread sums
    int inc = tsum;
    #pragma unroll
    for (int off = 1; off < 64; off <<= 1) {
        int n = __shfl_up(inc, off, 64);
        if (lane >= off) inc += n;
    }

    __shared__ int wsum[4];
    if (lane == 63) wsum[wv] = inc;
    __syncthreads();

    int base = 0;
    #pragma unroll
    for (int j = 0; j < 4; ++j) if (j < wv) base += wsum[j];
    const int blockTotal = wsum[0] + wsum[1] + wsum[2] + wsum[3];

    int p = base + inc - tsum;           // exclusive prefix for first elem
    int* __restrict__ m = idx_map + b * max_len;
    int src = b * S + t * 4;

    for (int k = 0; k < d0; ++k) m[p++] = src;
    ++src;
    for (int k = 0; k < d1; ++k) m[p++] = src;
    ++src;
    for (int k = 0; k < d2; ++k) m[p++] = src;
    ++src;
    for (int k = 0; k < d3; ++k) m[p++] = src;

    for (int q = blockTotal + t; q < max_len; q += 256) m[q] = -1;
}

// ---- Kernel B: persistent chunked gather, one wave per row-chunk -----------
// Each wave owns rows [w*chunk, (w+1)*chunk); 2 rows per iteration with all
// loads issued before stores; NT stores keep x resident in L2/L3.
__global__ void lr_gather(const f4* __restrict__ x4,
                          const int* __restrict__ idx_map,
                          f4* __restrict__ out,
                          int n_rows, int rows_per_wave) {
    const int wave = (blockIdx.x * blockDim.x + threadIdx.x) >> 6;
    const int lane = threadIdx.x & 63;

    int r = wave * rows_per_wave;
    int r_end = r + rows_per_wave;
    if (r_end > n_rows) r_end = n_rows;
    if (r >= r_end) return;

    for (; r + 2 <= r_end; r += 2) {
        const int i0 = __builtin_amdgcn_readfirstlane(idx_map[r]);
        const int i1 = __builtin_amdgcn_readfirstlane(idx_map[r + 1]);

        f4 a0 = {0.f,0.f,0.f,0.f}, c0 = {0.f,0.f,0.f,0.f};
        f4 a1 = {0.f,0.f,0.f,0.f}, c1 = {0.f,0.f,0.f,0.f};
        if (i0 >= 0) {
            const f4* __restrict__ s0 = x4 + (size_t)i0 * VEC_PER_ROW;
            a0 = s0[lane]; c0 = s0[lane + 64];
        }
        if (i1 >= 0) {
            const f4* __restrict__ s1 = x4 + (size_t)i1 * VEC_PER_ROW;
            a1 = s1[lane]; c1 = s1[lane + 64];
        }
        f4* __restrict__ d0 = out + (size_t)r * VEC_PER_ROW;
        __builtin_nontemporal_store(a0, d0 + lane);
        __builtin_nontemporal_store(c0, d0 + lane + 64);
        f4* __restrict__ d1 = d0 + VEC_PER_ROW;
        __builtin_nontemporal_store(a1, d1 + lane);
        __builtin_nontemporal_store(c1, d1 + lane + 64);
    }
    if (r < r_end) {
        const int i0 = __builtin_amdgcn_readfirstlane(idx_map[r]);
        f4 a0 = {0.f,0.f,0.f,0.f}, c0 = {0.f,0.f,0.f,0.f};
        if (i0 >= 0) {
            const f4* __restrict__ s0 = x4 + (size_t)i0 * VEC_PER_ROW;
            a0 = s0[lane]; c0 = s0[lane + 64];
        }
        f4* __restrict__ d0 = out + (size_t)r * VEC_PER_ROW;
        __builtin_nontemporal_store(a0, d0 + lane);
        __builtin_nontemporal_store(c0, d0 + lane + 64);
    }
}

extern "C" void kernel_launch(void* const* d_in, const int* in_sizes, int n_in,
                              void* d_out, int out_size, void* d_ws, size_t ws_size,
                              hipStream_t stream) {
    const float* x = (const float*)d_in[0];
    const int* durations = (const int*)d_in[1];
    float* out = (float*)d_out;

    int* idx_map = (int*)d_ws;                    // B*max_len*4 bytes (<1 MB)

    const int max_len = out_size / (B * D);

    lr_scan_scatter<<<B, 256, 0, stream>>>(durations, idx_map, max_len);

    const int n_rows = out_size / D;              // B * max_len
    const int grid = 2048;                        // 8 blocks/CU, 4 waves each
    const int n_waves = grid * 4;
    const int rows_per_wave = (n_rows + n_waves - 1) / n_waves;
    lr_gather<<<grid, 256, 0, stream>>>(
        (const f4*)x, idx_map, (f4*)out, n_rows, rows_per_wave);
}

// Round 5
// 57.223 us; speedup vs baseline: 1.0837x; 1.0837x over previous
//
#include <hip/hip_runtime.h>
#include <hip/hip_bf16.h>

// LengthRegulator: x (B,S,D) f32, durations (B,S) int.
// dur = clip(dur,1,None); cum = cumsum(dur, axis=1); totals = cum[:,-1];
// out[b,p,:] = x[b, searchsorted_right(cum[b], p) clipped S-1, :] for p < totals[b], else 0.
// Output (B, max_len, D), max_len = out_size/(B*D).

constexpr int B = 32;
constexpr int S = 1024;
constexpr int D = 512;
constexpr int VEC_PER_ROW = D / 4;       // 128 float4 per row

using f4 = __attribute__((ext_vector_type(4))) float;

// ---- Kernel A: per-batch scan (wave-scan, 4 elems/thread) + scatter --------
__global__ void lr_scan_scatter(const int* __restrict__ durations,
                                int* __restrict__ idx_map,
                                int max_len) {
    const int b    = blockIdx.x;
    const int t    = threadIdx.x;        // 0..255
    const int lane = t & 63;
    const int wv   = t >> 6;             // wave id 0..3

    int4 d4 = reinterpret_cast<const int4*>(durations + b * S)[t];
    const int d0 = d4.x < 1 ? 1 : d4.x;
    const int d1 = d4.y < 1 ? 1 : d4.y;
    const int d2 = d4.z < 1 ? 1 : d4.z;
    const int d3 = d4.w < 1 ? 1 : d4.w;
    const int tsum = d0 + d1 + d2 + d3;

    int inc = tsum;
    #pragma unroll
    for (int off = 1; off < 64; off <<= 1) {
        int n = __shfl_up(inc, off, 64);
        if (lane >= off) inc += n;
    }

    __shared__ int wsum[4];
    if (lane == 63) wsum[wv] = inc;
    __syncthreads();

    int base = 0;
    #pragma unroll
    for (int j = 0; j < 4; ++j) if (j < wv) base += wsum[j];
    const int blockTotal = wsum[0] + wsum[1] + wsum[2] + wsum[3];

    int p = base + inc - tsum;           // exclusive prefix for first elem
    int* __restrict__ m = idx_map + b * max_len;
    int src = b * S + t * 4;

    for (int k = 0; k < d0; ++k) m[p++] = src;
    ++src;
    for (int k = 0; k < d1; ++k) m[p++] = src;
    ++src;
    for (int k = 0; k < d2; ++k) m[p++] = src;
    ++src;
    for (int k = 0; k < d3; ++k) m[p++] = src;

    for (int q = blockTotal + t; q < max_len; q += 256) m[q] = -1;
}

// ---- Kernel B: persistent gather, 4 rows/iter, pipelined idx prefetch ------
__global__ void lr_gather(const f4* __restrict__ x4,
                          const int* __restrict__ idx_map,
                          f4* __restrict__ out,
                          int n_rows, int rows_per_wave) {
    const int wave = (blockIdx.x * blockDim.x + threadIdx.x) >> 6;
    const int lane = threadIdx.x & 63;

    int r = wave * rows_per_wave;
    int r_end = r + rows_per_wave;
    if (r_end > n_rows) r_end = n_rows;
    if (r >= r_end) return;

    // pipelined idx: one per-lane load covers 4 rows (lanes 0..3)
    int my = (r + 4 <= r_end) ? idx_map[r + (lane & 3)] : 0;

    while (r + 4 <= r_end) {
        const int i0 = __builtin_amdgcn_readfirstlane(__shfl(my, 0, 64));
        const int i1 = __builtin_amdgcn_readfirstlane(__shfl(my, 1, 64));
        const int i2 = __builtin_amdgcn_readfirstlane(__shfl(my, 2, 64));
        const int i3 = __builtin_amdgcn_readfirstlane(__shfl(my, 3, 64));

        f4 a0 = {0,0,0,0}, c0 = {0,0,0,0};
        f4 a1 = {0,0,0,0}, c1 = {0,0,0,0};
        f4 a2 = {0,0,0,0}, c2 = {0,0,0,0};
        f4 a3 = {0,0,0,0}, c3 = {0,0,0,0};
        if (i0 >= 0) { const f4* s = x4 + (size_t)i0 * VEC_PER_ROW; a0 = s[lane]; c0 = s[lane + 64]; }
        if (i1 >= 0) { const f4* s = x4 + (size_t)i1 * VEC_PER_ROW; a1 = s[lane]; c1 = s[lane + 64]; }
        if (i2 >= 0) { const f4* s = x4 + (size_t)i2 * VEC_PER_ROW; a2 = s[lane]; c2 = s[lane + 64]; }
        if (i3 >= 0) { const f4* s = x4 + (size_t)i3 * VEC_PER_ROW; a3 = s[lane]; c3 = s[lane + 64]; }

        const int rn = r + 4;
        // prefetch next iteration's idx before the stores
        if (rn + 4 <= r_end) my = idx_map[rn + (lane & 3)];

        f4* __restrict__ d = out + (size_t)r * VEC_PER_ROW;
        __builtin_nontemporal_store(a0, d + lane);
        __builtin_nontemporal_store(c0, d + lane + 64);
        __builtin_nontemporal_store(a1, d + VEC_PER_ROW + lane);
        __builtin_nontemporal_store(c1, d + VEC_PER_ROW + lane + 64);
        __builtin_nontemporal_store(a2, d + 2 * VEC_PER_ROW + lane);
        __builtin_nontemporal_store(c2, d + 2 * VEC_PER_ROW + lane + 64);
        __builtin_nontemporal_store(a3, d + 3 * VEC_PER_ROW + lane);
        __builtin_nontemporal_store(c3, d + 3 * VEC_PER_ROW + lane + 64);

        r = rn;
    }
    // tail (only the last wave can land here)
    for (; r < r_end; ++r) {
        const int i0 = __builtin_amdgcn_readfirstlane(idx_map[r]);
        f4 a = {0,0,0,0}, c = {0,0,0,0};
        if (i0 >= 0) { const f4* s = x4 + (size_t)i0 * VEC_PER_ROW; a = s[lane]; c = s[lane + 64]; }
        f4* __restrict__ d = out + (size_t)r * VEC_PER_ROW;
        __builtin_nontemporal_store(a, d + lane);
        __builtin_nontemporal_store(c, d + lane + 64);
    }
}

extern "C" void kernel_launch(void* const* d_in, const int* in_sizes, int n_in,
                              void* d_out, int out_size, void* d_ws, size_t ws_size,
                              hipStream_t stream) {
    const float* x = (const float*)d_in[0];
    const int* durations = (const int*)d_in[1];
    float* out = (float*)d_out;

    int* idx_map = (int*)d_ws;                    // B*max_len*4 bytes (<1 MB)

    const int max_len = out_size / (B * D);

    lr_scan_scatter<<<B, 256, 0, stream>>>(durations, idx_map, max_len);

    const int n_rows = out_size / D;              // B * max_len
    const int grid = 2048;                        // 8 blocks/CU, 4 waves each
    const int n_waves = grid * 4;
    int rows_per_wave = (n_rows + n_waves - 1) / n_waves;
    rows_per_wave = (rows_per_wave + 3) & ~3;     // multiple of 4 -> no tail
    lr_gather<<<grid, 256, 0, stream>>>(
        (const f4*)x, idx_map, (f4*)out, n_rows, rows_per_wave);
}

// Round 6
// 55.099 us; speedup vs baseline: 1.1255x; 1.0386x over previous
//
#include <hip/hip_runtime.h>
#include <hip/hip_bf16.h>

// LengthRegulator: x (B,S,D) f32, durations (B,S) int.
// dur = clip(dur,1,None); cum = cumsum(dur, axis=1); totals = cum[:,-1];
// out[b,p,:] = x[b, searchsorted_right(cum[b], p), :] for p < totals[b], else 0.
// Output (B, max_len, D), max_len = out_size/(B*D).
//
// Fused single kernel: each block owns a ~60-row chunk of one batch's output.
// It redundantly scans its batch's 1024 durations (cheap, overlapped across
// all 2048 blocks), scatters source-row indices for its chunk into LDS, then
// streams the copy with NT stores.

constexpr int B = 32;
constexpr int S = 1024;
constexpr int D = 512;
constexpr int VEC = D / 4;               // 128 float4 per row
constexpr int BPB = 64;                  // blocks per batch
constexpr int MAX_RPB = 128;             // max_len <= 7*1024 -> rpb <= 112

using f4 = __attribute__((ext_vector_type(4))) float;

__global__ void lr_fused(const int* __restrict__ durations,
                         const f4* __restrict__ x4,
                         f4* __restrict__ out,
                         int max_len) {
    const int b   = blockIdx.x >> 6;     // batch
    const int blk = blockIdx.x & (BPB - 1);
    const int rpb = (max_len + BPB - 1) / BPB;
    const int p0  = blk * rpb;
    const int p1  = min(p0 + rpb, max_len);
    if (p0 >= p1) return;                // uniform across block

    const int t    = threadIdx.x;        // 0..255
    const int lane = t & 63;
    const int wv   = t >> 6;

    __shared__ int wsum[4];
    __shared__ int s_idx[MAX_RPB];

    // ---- local scan of this batch's clipped durations (4 elems/thread) ----
    int4 d4 = reinterpret_cast<const int4*>(durations + b * S)[t];
    const int d0 = d4.x < 1 ? 1 : d4.x;
    const int d1 = d4.y < 1 ? 1 : d4.y;
    const int d2 = d4.z < 1 ? 1 : d4.z;
    const int d3 = d4.w < 1 ? 1 : d4.w;
    const int tsum = d0 + d1 + d2 + d3;

    int inc = tsum;
    #pragma unroll
    for (int off = 1; off < 64; off <<= 1) {
        int n = __shfl_up(inc, off, 64);
        if (lane >= off) inc += n;
    }
    if (lane == 63) wsum[wv] = inc;

    const int nblk = p1 - p0;
    for (int q = t; q < nblk; q += 256) s_idx[q] = -1;  // masked tail default
    __syncthreads();

    int base = 0;
    #pragma unroll
    for (int j = 0; j < 4; ++j) if (j < wv) base += wsum[j];

    // ---- scatter source indices intersecting [p0, p1) into LDS ----
    int p = base + inc - tsum;           // global exclusive prefix, elem 0
    int src = b * S + t * 4;
    {
        int e;
        e = p + d0; for (int q = max(p, p0); q < min(e, p1); ++q) s_idx[q - p0] = src; p = e; ++src;
        e = p + d1; for (int q = max(p, p0); q < min(e, p1); ++q) s_idx[q - p0] = src; p = e; ++src;
        e = p + d2; for (int q = max(p, p0); q < min(e, p1); ++q) s_idx[q - p0] = src; p = e; ++src;
        e = p + d3; for (int q = max(p, p0); q < min(e, p1); ++q) s_idx[q - p0] = src;
    }
    __syncthreads();

    // ---- streaming copy: wave wv owns rows [r, r1) of the chunk ----
    const int qr = (nblk + 3) >> 2;
    int r  = wv * qr;
    int r1 = min(r + qr, nblk);

    f4* __restrict__ dbase = out + ((size_t)b * max_len + p0) * VEC;

    for (; r + 4 <= r1; r += 4) {
        const int i0 = __builtin_amdgcn_readfirstlane(s_idx[r]);
        const int i1 = __builtin_amdgcn_readfirstlane(s_idx[r + 1]);
        const int i2 = __builtin_amdgcn_readfirstlane(s_idx[r + 2]);
        const int i3 = __builtin_amdgcn_readfirstlane(s_idx[r + 3]);

        f4 a0 = {0,0,0,0}, c0 = {0,0,0,0};
        f4 a1 = {0,0,0,0}, c1 = {0,0,0,0};
        f4 a2 = {0,0,0,0}, c2 = {0,0,0,0};
        f4 a3 = {0,0,0,0}, c3 = {0,0,0,0};
        if (i0 >= 0) { const f4* s = x4 + (size_t)i0 * VEC; a0 = s[lane]; c0 = s[lane + 64]; }
        if (i1 >= 0) { const f4* s = x4 + (size_t)i1 * VEC; a1 = s[lane]; c1 = s[lane + 64]; }
        if (i2 >= 0) { const f4* s = x4 + (size_t)i2 * VEC; a2 = s[lane]; c2 = s[lane + 64]; }
        if (i3 >= 0) { const f4* s = x4 + (size_t)i3 * VEC; a3 = s[lane]; c3 = s[lane + 64]; }

        f4* __restrict__ d = dbase + (size_t)r * VEC;
        __builtin_nontemporal_store(a0, d + lane);
        __builtin_nontemporal_store(c0, d + lane + 64);
        __builtin_nontemporal_store(a1, d + VEC + lane);
        __builtin_nontemporal_store(c1, d + VEC + lane + 64);
        __builtin_nontemporal_store(a2, d + 2 * VEC + lane);
        __builtin_nontemporal_store(c2, d + 2 * VEC + lane + 64);
        __builtin_nontemporal_store(a3, d + 3 * VEC + lane);
        __builtin_nontemporal_store(c3, d + 3 * VEC + lane + 64);
    }
    for (; r < r1; ++r) {
        const int i0 = __builtin_amdgcn_readfirstlane(s_idx[r]);
        f4 a = {0,0,0,0}, c = {0,0,0,0};
        if (i0 >= 0) { const f4* s = x4 + (size_t)i0 * VEC; a = s[lane]; c = s[lane + 64]; }
        f4* __restrict__ d = dbase + (size_t)r * VEC;
        __builtin_nontemporal_store(a, d + lane);
        __builtin_nontemporal_store(c, d + lane + 64);
    }
}

extern "C" void kernel_launch(void* const* d_in, const int* in_sizes, int n_in,
                              void* d_out, int out_size, void* d_ws, size_t ws_size,
                              hipStream_t stream) {
    const float* x = (const float*)d_in[0];
    const int* durations = (const int*)d_in[1];
    float* out = (float*)d_out;

    const int max_len = out_size / (B * D);

    lr_fused<<<B * BPB, 256, 0, stream>>>(
        durations, (const f4*)x, (f4*)out, max_len);
}

// Round 7
// 53.398 us; speedup vs baseline: 1.1613x; 1.0318x over previous
//
#include <hip/hip_runtime.h>
#include <hip/hip_bf16.h>

// LengthRegulator: x (B,S,D) f32, durations (B,S) int.
// dur = clip(dur,1,None); cum = cumsum(dur, axis=1); totals = cum[:,-1];
// out[b,p,:] = x[b, searchsorted_right(cum[b], p), :] for p < totals[b], else 0.
// Output (B, max_len, D), max_len = out_size/(B*D).
//
// Fused, 1024-thread blocks: each block owns a ~1/16 chunk of one batch's
// output rows. Scan of the batch's 1024 durations is done once per block
// (1 elem/thread, wave-scan + LDS combine), source indices for the chunk are
// scattered into LDS, then a 16-wave streaming copy with NT stores.

constexpr int B = 32;
constexpr int S = 1024;
constexpr int D = 512;
constexpr int VEC = D / 4;               // 128 float4 per row
constexpr int BPB = 16;                  // blocks per batch
constexpr int NW  = 16;                  // waves per block (1024 threads)
constexpr int MAX_RPB = 320;             // rpb = ceil(max_len/16) <= 320 (max_len<=5120)

using f4 = __attribute__((ext_vector_type(4))) float;

__global__ __launch_bounds__(1024, 2)
void lr_fused(const int* __restrict__ durations,
              const f4* __restrict__ x4,
              f4* __restrict__ out,
              int max_len) {
    const int b   = blockIdx.x >> 4;     // batch
    const int blk = blockIdx.x & (BPB - 1);
    const int rpb = (max_len + BPB - 1) / BPB;
    const int p0  = blk * rpb;
    const int p1  = min(p0 + rpb, max_len);
    if (p0 >= p1) return;                // uniform across block

    const int t    = threadIdx.x;        // 0..1023
    const int lane = t & 63;
    const int wv   = t >> 6;             // 0..15

    __shared__ int wsum[NW];
    __shared__ int s_idx[MAX_RPB];

    // ---- scan of this batch's clipped durations, 1 elem/thread ----
    int d = durations[b * S + t];
    if (d < 1) d = 1;

    int inc = d;
    #pragma unroll
    for (int off = 1; off < 64; off <<= 1) {
        int n = __shfl_up(inc, off, 64);
        if (lane >= off) inc += n;
    }
    if (lane == 63) wsum[wv] = inc;

    const int nblk = p1 - p0;
    for (int q = t; q < nblk; q += 1024) s_idx[q] = -1;   // masked-tail default
    __syncthreads();

    int base = 0;
    #pragma unroll
    for (int j = 0; j < NW; ++j) if (j < wv) base += wsum[j];

    // ---- scatter source indices intersecting [p0, p1) into LDS ----
    const int pstart = base + inc - d;   // exclusive prefix
    const int pend   = pstart + d;
    const int src    = b * S + t;
    for (int q = max(pstart, p0); q < min(pend, p1); ++q) s_idx[q - p0] = src;
    __syncthreads();

    // ---- streaming copy: wave wv owns rows [r, r1) of the chunk ----
    const int qr = (nblk + NW - 1) / NW;
    int r  = wv * qr;
    int r1 = min(r + qr, nblk);

    f4* __restrict__ dbase = out + ((size_t)b * max_len + p0) * VEC;

    for (; r + 4 <= r1; r += 4) {
        const int i0 = __builtin_amdgcn_readfirstlane(s_idx[r]);
        const int i1 = __builtin_amdgcn_readfirstlane(s_idx[r + 1]);
        const int i2 = __builtin_amdgcn_readfirstlane(s_idx[r + 2]);
        const int i3 = __builtin_amdgcn_readfirstlane(s_idx[r + 3]);

        f4 a0 = {0,0,0,0}, c0 = {0,0,0,0};
        f4 a1 = {0,0,0,0}, c1 = {0,0,0,0};
        f4 a2 = {0,0,0,0}, c2 = {0,0,0,0};
        f4 a3 = {0,0,0,0}, c3 = {0,0,0,0};
        if (i0 >= 0) { const f4* s = x4 + (size_t)i0 * VEC; a0 = s[lane]; c0 = s[lane + 64]; }
        if (i1 >= 0) { const f4* s = x4 + (size_t)i1 * VEC; a1 = s[lane]; c1 = s[lane + 64]; }
        if (i2 >= 0) { const f4* s = x4 + (size_t)i2 * VEC; a2 = s[lane]; c2 = s[lane + 64]; }
        if (i3 >= 0) { const f4* s = x4 + (size_t)i3 * VEC; a3 = s[lane]; c3 = s[lane + 64]; }

        f4* __restrict__ dst = dbase + (size_t)r * VEC;
        __builtin_nontemporal_store(a0, dst + lane);
        __builtin_nontemporal_store(c0, dst + lane + 64);
        __builtin_nontemporal_store(a1, dst + VEC + lane);
        __builtin_nontemporal_store(c1, dst + VEC + lane + 64);
        __builtin_nontemporal_store(a2, dst + 2 * VEC + lane);
        __builtin_nontemporal_store(c2, dst + 2 * VEC + lane + 64);
        __builtin_nontemporal_store(a3, dst + 3 * VEC + lane);
        __builtin_nontemporal_store(c3, dst + 3 * VEC + lane + 64);
    }
    for (; r < r1; ++r) {
        const int i0 = __builtin_amdgcn_readfirstlane(s_idx[r]);
        f4 a = {0,0,0,0}, c = {0,0,0,0};
        if (i0 >= 0) { const f4* s = x4 + (size_t)i0 * VEC; a = s[lane]; c = s[lane + 64]; }
        f4* __restrict__ dst = dbase + (size_t)r * VEC;
        __builtin_nontemporal_store(a, dst + lane);
        __builtin_nontemporal_store(c, dst + lane + 64);
    }
}

extern "C" void kernel_launch(void* const* d_in, const int* in_sizes, int n_in,
                              void* d_out, int out_size, void* d_ws, size_t ws_size,
                              hipStream_t stream) {
    const float* x = (const float*)d_in[0];
    const int* durations = (const int*)d_in[1];
    float* out = (float*)d_out;

    const int max_len = out_size / (B * D);

    lr_fused<<<B * BPB, 1024, 0, stream>>>(
        durations, (const f4*)x, (f4*)out, max_len);
}